// Round 1
// baseline (2750.037 us; speedup 1.0000x reference)
//
#include <hip/hip_runtime.h>
#include <hip/hip_fp16.h>

// Problem constants
#define MTOK 8192   // B*S
#define DDIM 4096   // D
#define IDIM 11008  // I

// GEMM tiling
#define BM 128
#define BN 128
#define BK 64

typedef _Float16 f16x4 __attribute__((ext_vector_type(4)));
typedef _Float16 f16x8 __attribute__((ext_vector_type(8)));
typedef float    f32x4 __attribute__((ext_vector_type(4)));

// ---------------- conversion kernels ----------------
__global__ __launch_bounds__(256) void cvt_x_kernel(const float* __restrict__ src,
                                                    _Float16* __restrict__ dst, int n4) {
  int stride = gridDim.x * blockDim.x;
  for (int i = blockIdx.x * blockDim.x + threadIdx.x; i < n4; i += stride) {
    float4 v = ((const float4*)src)[i];
    f16x4 h;
    h.x = (_Float16)v.x; h.y = (_Float16)v.y; h.z = (_Float16)v.z; h.w = (_Float16)v.w;
    ((f16x4*)dst)[i] = h;
  }
}

__global__ __launch_bounds__(256) void cvt_w_kernel(const int* __restrict__ src,
                                                    _Float16* __restrict__ dst, int n4) {
  int stride = gridDim.x * blockDim.x;
  for (int i = blockIdx.x * blockDim.x + threadIdx.x; i < n4; i += stride) {
    int4 v = ((const int4*)src)[i];
    f16x4 h;  // int8-range values are exact in f16
    h.x = (_Float16)v.x; h.y = (_Float16)v.y; h.z = (_Float16)v.z; h.w = (_Float16)v.w;
    ((f16x4*)dst)[i] = h;
  }
}

// ---------------- GEMM helpers ----------------
// LDS tile layout: [row 0..127][chunk 0..7], chunk = 8 f16 = 16B.
// Chunk at LDS (r, c) holds global chunk (r, c ^ (r&7)).
// -> global_load_lds stays lane-contiguous (no padding allowed) while
//    frag reads land 2 lanes/bank-group (free per m136).
__device__ __forceinline__ void stage_tile(const _Float16* __restrict__ gbase, int ldk,
                                           _Float16* stile, int tid) {
#pragma unroll
  for (int it = 0; it < 4; ++it) {
    int slot = it * 256 + tid;          // 1024 chunks of 16B = 128x64 f16
    int r = slot >> 3, c = slot & 7;
    int csrc = c ^ (r & 7);
    const _Float16* gp = gbase + (long)r * ldk + csrc * 8;
    __builtin_amdgcn_global_load_lds(
        (const __attribute__((address_space(1))) void*)gp,
        (__attribute__((address_space(3))) void*)(stile + slot * 8),
        16, 0, 0);
  }
}

__device__ __forceinline__ f16x8 frag_ld(const _Float16* s, int row, int cbase) {
  int c = cbase ^ (row & 7);
  return *(const f16x8*)(s + (row * 8 + c) * 8);
}

// ---------------- fused gate/up GEMM + SwiGLU epilogue ----------------
// X:[MTOK,DDIM] f16, Wg/Wu:[IDIM,DDIM] f16 (B^T form), H:[MTOK,IDIM] f16 scaled by 1/256
__global__ __launch_bounds__(256, 2) void gemm_gateup(
    const _Float16* __restrict__ X, const _Float16* __restrict__ Wg,
    const _Float16* __restrict__ Wu, const float* __restrict__ gs_p,
    const float* __restrict__ us_p, _Float16* __restrict__ H) {
  __shared__ _Float16 sA[BM * BK] __attribute__((aligned(16)));
  __shared__ _Float16 sG[BN * BK] __attribute__((aligned(16)));
  __shared__ _Float16 sU[BN * BK] __attribute__((aligned(16)));

  int tid = threadIdx.x;
  int bm = blockIdx.x, bn = blockIdx.y;  // bm fastest: concurrent blocks share weight panels less, re-read smaller A from L3
  int lane = tid & 63, w = tid >> 6;
  int wr = (w >> 1) * 64, wc = (w & 1) * 64;
  int lr = lane & 15, q = lane >> 4;

  const _Float16* Abase = X + (long)bm * BM * DDIM;
  const _Float16* Gbase = Wg + (long)bn * BN * DDIM;
  const _Float16* Ubase = Wu + (long)bn * BN * DDIM;

  f32x4 accg[4][4], accu[4][4];
#pragma unroll
  for (int i = 0; i < 4; ++i)
#pragma unroll
    for (int j = 0; j < 4; ++j) {
      accg[i][j] = (f32x4){0.f, 0.f, 0.f, 0.f};
      accu[i][j] = (f32x4){0.f, 0.f, 0.f, 0.f};
    }

  for (int k0 = 0; k0 < DDIM; k0 += BK) {
    stage_tile(Abase + k0, DDIM, sA, tid);
    stage_tile(Gbase + k0, DDIM, sG, tid);
    stage_tile(Ubase + k0, DDIM, sU, tid);
    __syncthreads();
#pragma unroll
    for (int kk = 0; kk < 2; ++kk) {
      int cbase = kk * 4 + q;  // 16B chunk index for k = kk*32 + q*8
      f16x8 a[4], bg[4], bu[4];
#pragma unroll
      for (int i = 0; i < 4; ++i) a[i] = frag_ld(sA, wr + i * 16 + lr, cbase);
#pragma unroll
      for (int j = 0; j < 4; ++j) {
        bg[j] = frag_ld(sG, wc + j * 16 + lr, cbase);
        bu[j] = frag_ld(sU, wc + j * 16 + lr, cbase);
      }
#pragma unroll
      for (int i = 0; i < 4; ++i)
#pragma unroll
        for (int j = 0; j < 4; ++j) {
          accg[i][j] = __builtin_amdgcn_mfma_f32_16x16x32_f16(a[i], bg[j], accg[i][j], 0, 0, 0);
          accu[i][j] = __builtin_amdgcn_mfma_f32_16x16x32_f16(a[i], bu[j], accu[i][j], 0, 0, 0);
        }
    }
    __syncthreads();
  }

  float gs = gs_p[0], us = us_p[0];
  // C/D layout (verified, dtype-independent): col = lane&15, row = q*4 + reg
#pragma unroll
  for (int i = 0; i < 4; ++i)
#pragma unroll
    for (int j = 0; j < 4; ++j)
#pragma unroll
      for (int r = 0; r < 4; ++r) {
        long m = (long)bm * BM + wr + i * 16 + q * 4 + r;
        long n = (long)bn * BN + wc + j * 16 + lr;
        float g = accg[i][j][r] * gs;
        float u = accu[i][j][r] * us;
        float sg = g / (1.0f + __expf(-g));  // silu
        H[m * IDIM + n] = (_Float16)(sg * u * 0.00390625f);  // /256 to keep f16 range safe
      }
}

// ---------------- down-proj GEMM ----------------
// Hin:[MTOK,IDIM] f16 (scaled 1/256), Wd:[DDIM,IDIM] f16, Out:[MTOK,DDIM] f32
__global__ __launch_bounds__(256, 2) void gemm_down(
    const _Float16* __restrict__ Hin, const _Float16* __restrict__ Wd,
    const float* __restrict__ ds_p, float* __restrict__ Out) {
  __shared__ _Float16 sA[BM * BK] __attribute__((aligned(16)));
  __shared__ _Float16 sB[BN * BK] __attribute__((aligned(16)));

  int tid = threadIdx.x;
  int bm = blockIdx.x, bn = blockIdx.y;
  int lane = tid & 63, w = tid >> 6;
  int wr = (w >> 1) * 64, wc = (w & 1) * 64;
  int lr = lane & 15, q = lane >> 4;

  const _Float16* Abase = Hin + (long)bm * BM * IDIM;
  const _Float16* Bbase = Wd + (long)bn * BN * IDIM;

  f32x4 acc[4][4];
#pragma unroll
  for (int i = 0; i < 4; ++i)
#pragma unroll
    for (int j = 0; j < 4; ++j) acc[i][j] = (f32x4){0.f, 0.f, 0.f, 0.f};

  for (int k0 = 0; k0 < IDIM; k0 += BK) {
    stage_tile(Abase + k0, IDIM, sA, tid);
    stage_tile(Bbase + k0, IDIM, sB, tid);
    __syncthreads();
#pragma unroll
    for (int kk = 0; kk < 2; ++kk) {
      int cbase = kk * 4 + q;
      f16x8 a[4], b[4];
#pragma unroll
      for (int i = 0; i < 4; ++i) a[i] = frag_ld(sA, wr + i * 16 + lr, cbase);
#pragma unroll
      for (int j = 0; j < 4; ++j) b[j] = frag_ld(sB, wc + j * 16 + lr, cbase);
#pragma unroll
      for (int i = 0; i < 4; ++i)
#pragma unroll
        for (int j = 0; j < 4; ++j)
          acc[i][j] = __builtin_amdgcn_mfma_f32_16x16x32_f16(a[i], b[j], acc[i][j], 0, 0, 0);
    }
    __syncthreads();
  }

  float scale = ds_p[0] * 256.0f;  // undo the 1/256 on H
#pragma unroll
  for (int i = 0; i < 4; ++i)
#pragma unroll
    for (int j = 0; j < 4; ++j)
#pragma unroll
      for (int r = 0; r < 4; ++r) {
        long m = (long)bm * BM + wr + i * 16 + q * 4 + r;
        long n = (long)bn * BN + wc + j * 16 + lr;
        Out[m * DDIM + n] = acc[i][j][r] * scale;
      }
}

// ---------------- launch ----------------
// ws layout (bytes):
//   x_f16:   [0,          67108864)
//   gate_f16:[67108864,   157286400)
//   up_f16:  [157286400,  247463936)
//   down_f16:[247463936,  337641472)
//   h_f16:   [337641472,  517996544)
extern "C" void kernel_launch(void* const* d_in, const int* in_sizes, int n_in,
                              void* d_out, int out_size, void* d_ws, size_t ws_size,
                              hipStream_t stream) {
  const float* x  = (const float*)d_in[0];
  const int*   gw = (const int*)d_in[1];
  const float* gs = (const float*)d_in[2];
  const int*   uw = (const int*)d_in[3];
  const float* us = (const float*)d_in[4];
  const int*   dw = (const int*)d_in[5];
  const float* ds = (const float*)d_in[6];
  float* out = (float*)d_out;

  char* ws = (char*)d_ws;
  _Float16* xf  = (_Float16*)(ws);
  _Float16* gwf = (_Float16*)(ws + 67108864L);
  _Float16* uwf = (_Float16*)(ws + 157286400L);
  _Float16* dwf = (_Float16*)(ws + 247463936L);
  _Float16* h   = (_Float16*)(ws + 337641472L);

  cvt_x_kernel<<<2048, 256, 0, stream>>>(x, xf, (MTOK * DDIM) / 4);
  cvt_w_kernel<<<2048, 256, 0, stream>>>(gw, gwf, (IDIM * DDIM) / 4);
  cvt_w_kernel<<<2048, 256, 0, stream>>>(uw, uwf, (IDIM * DDIM) / 4);
  cvt_w_kernel<<<2048, 256, 0, stream>>>(dw, dwf, (DDIM * IDIM) / 4);

  dim3 g1(MTOK / BM, IDIM / BN);  // 64 x 86
  gemm_gateup<<<g1, 256, 0, stream>>>(xf, gwf, uwf, gs, us, h);

  dim3 g2(MTOK / BM, DDIM / BN);  // 64 x 32
  gemm_down<<<g2, 256, 0, stream>>>(h, dwf, ds, out);
}

// Round 2
// 2583.069 us; speedup vs baseline: 1.0646x; 1.0646x over previous
//
#include <hip/hip_runtime.h>
#include <hip/hip_fp16.h>

// Problem constants
#define MTOK 8192   // B*S
#define DDIM 4096   // D
#define IDIM 11008  // I

// GEMM tiling
#define BM 128
#define BN 128
#define BK 64

typedef _Float16 f16x4 __attribute__((ext_vector_type(4)));
typedef _Float16 f16x8 __attribute__((ext_vector_type(8)));
typedef float    f32x4 __attribute__((ext_vector_type(4)));

// ---------------- conversion kernels ----------------
__global__ __launch_bounds__(256) void cvt_x_kernel(const float* __restrict__ src,
                                                    _Float16* __restrict__ dst, int n4) {
  int stride = gridDim.x * blockDim.x;
  for (int i = blockIdx.x * blockDim.x + threadIdx.x; i < n4; i += stride) {
    float4 v = ((const float4*)src)[i];
    f16x4 h;
    h.x = (_Float16)v.x; h.y = (_Float16)v.y; h.z = (_Float16)v.z; h.w = (_Float16)v.w;
    ((f16x4*)dst)[i] = h;
  }
}

__global__ __launch_bounds__(256) void cvt_w_kernel(const int* __restrict__ src,
                                                    _Float16* __restrict__ dst, int n4) {
  int stride = gridDim.x * blockDim.x;
  for (int i = blockIdx.x * blockDim.x + threadIdx.x; i < n4; i += stride) {
    int4 v = ((const int4*)src)[i];
    f16x4 h;  // int8-range values are exact in f16
    h.x = (_Float16)v.x; h.y = (_Float16)v.y; h.z = (_Float16)v.z; h.w = (_Float16)v.w;
    ((f16x4*)dst)[i] = h;
  }
}

// ---------------- GEMM helpers ----------------
// LDS tile layout: [row 0..127][chunk 0..7], chunk = 8 f16 = 16B.
// Chunk at LDS (r, c) holds global chunk (r, c ^ (r&7)).
// -> global_load_lds stays lane-contiguous (no padding allowed) while
//    frag reads land 2 lanes/bank-group (free per m136).
__device__ __forceinline__ void stage_tile(const _Float16* __restrict__ gbase, int ldk,
                                           _Float16* stile, int tid) {
#pragma unroll
  for (int it = 0; it < 4; ++it) {
    int slot = it * 256 + tid;          // 1024 chunks of 16B = 128x64 f16
    int r = slot >> 3, c = slot & 7;
    int csrc = c ^ (r & 7);
    const _Float16* gp = gbase + (long)r * ldk + csrc * 8;
    __builtin_amdgcn_global_load_lds(
        (const __attribute__((address_space(1))) void*)gp,
        (__attribute__((address_space(3))) void*)(stile + slot * 8),
        16, 0, 0);
  }
}

__device__ __forceinline__ f16x8 frag_ld(const _Float16* s, int row, int cbase) {
  int c = cbase ^ (row & 7);
  return *(const f16x8*)(s + (row * 8 + c) * 8);
}

// ---------------- fused gate/up GEMM + SwiGLU epilogue ----------------
// X:[MTOK,DDIM] f16, Wg/Wu:[IDIM,DDIM] f16 (B^T form), H:[MTOK,IDIM] f16 scaled by 1/256
__global__ __launch_bounds__(256, 2) void gemm_gateup(
    const _Float16* __restrict__ X, const _Float16* __restrict__ Wg,
    const _Float16* __restrict__ Wu, const float* __restrict__ gs_p,
    const float* __restrict__ us_p, _Float16* __restrict__ H) {
  __shared__ _Float16 sA[BM * BK] __attribute__((aligned(16)));
  __shared__ _Float16 sG[BN * BK] __attribute__((aligned(16)));
  __shared__ _Float16 sU[BN * BK] __attribute__((aligned(16)));

  int tid = threadIdx.x;
  int bm = blockIdx.x, bn = blockIdx.y;
  int lane = tid & 63, w = tid >> 6;
  int wr = (w >> 1) * 64, wc = (w & 1) * 64;
  int lr = lane & 15, q = lane >> 4;

  const _Float16* Abase = X + (long)bm * BM * DDIM;
  const _Float16* Gbase = Wg + (long)bn * BN * DDIM;
  const _Float16* Ubase = Wu + (long)bn * BN * DDIM;

  f32x4 accg[4][4], accu[4][4];
#pragma unroll
  for (int i = 0; i < 4; ++i)
#pragma unroll
    for (int j = 0; j < 4; ++j) {
      accg[i][j] = (f32x4){0.f, 0.f, 0.f, 0.f};
      accu[i][j] = (f32x4){0.f, 0.f, 0.f, 0.f};
    }

  for (int k0 = 0; k0 < DDIM; k0 += BK) {
    stage_tile(Abase + k0, DDIM, sA, tid);
    stage_tile(Gbase + k0, DDIM, sG, tid);
    stage_tile(Ubase + k0, DDIM, sU, tid);
    __syncthreads();
#pragma unroll
    for (int kk = 0; kk < 2; ++kk) {
      int cbase = kk * 4 + q;  // 16B chunk index for k = kk*32 + q*8
      f16x8 a[4], bg[4], bu[4];
#pragma unroll
      for (int i = 0; i < 4; ++i) a[i] = frag_ld(sA, wr + i * 16 + lr, cbase);
#pragma unroll
      for (int j = 0; j < 4; ++j) {
        bg[j] = frag_ld(sG, wc + j * 16 + lr, cbase);
        bu[j] = frag_ld(sU, wc + j * 16 + lr, cbase);
      }
#pragma unroll
      for (int i = 0; i < 4; ++i)
#pragma unroll
        for (int j = 0; j < 4; ++j) {
          accg[i][j] = __builtin_amdgcn_mfma_f32_16x16x32_f16(a[i], bg[j], accg[i][j], 0, 0, 0);
          accu[i][j] = __builtin_amdgcn_mfma_f32_16x16x32_f16(a[i], bu[j], accu[i][j], 0, 0, 0);
        }
    }
    __syncthreads();
  }

  float gs = gs_p[0], us = us_p[0];
  // C/D layout (verified, dtype-independent): col = lane&15, row = q*4 + reg
#pragma unroll
  for (int i = 0; i < 4; ++i)
#pragma unroll
    for (int j = 0; j < 4; ++j)
#pragma unroll
      for (int r = 0; r < 4; ++r) {
        long m = (long)bm * BM + wr + i * 16 + q * 4 + r;
        long n = (long)bn * BN + wc + j * 16 + lr;
        float g = accg[i][j][r] * gs;
        float u = accu[i][j][r] * us;
        float sg = g / (1.0f + __expf(-g));  // silu
        H[m * IDIM + n] = (_Float16)(sg * u * 0.00390625f);  // /256 to keep f16 range safe
      }
}

// ---------------- down-proj GEMM (paired-BN: one A tile, two B tiles) ----------------
// Hin:[MTOK,IDIM] f16 (scaled 1/256), Wd:[DDIM,IDIM] f16, Out:[MTOK,DDIM] f32
// Each block computes a 128(m) x 256(n) output tile: A staged once, shared by
// two Wd panels -> 64 MFMA per 3 staged tiles (same economics as gemm_gateup).
__global__ __launch_bounds__(256, 2) void gemm_down(
    const _Float16* __restrict__ Hin, const _Float16* __restrict__ Wd,
    const float* __restrict__ ds_p, float* __restrict__ Out) {
  __shared__ _Float16 sA[BM * BK] __attribute__((aligned(16)));
  __shared__ _Float16 sB0[BN * BK] __attribute__((aligned(16)));
  __shared__ _Float16 sB1[BN * BK] __attribute__((aligned(16)));

  int tid = threadIdx.x;
  int bm = blockIdx.x, bn = blockIdx.y;
  int lane = tid & 63, w = tid >> 6;
  int wr = (w >> 1) * 64, wc = (w & 1) * 64;
  int lr = lane & 15, q = lane >> 4;

  const _Float16* Abase = Hin + (long)bm * BM * IDIM;
  const _Float16* B0base = Wd + (long)(bn * 256) * IDIM;
  const _Float16* B1base = Wd + (long)(bn * 256 + 128) * IDIM;

  f32x4 acc0[4][4], acc1[4][4];
#pragma unroll
  for (int i = 0; i < 4; ++i)
#pragma unroll
    for (int j = 0; j < 4; ++j) {
      acc0[i][j] = (f32x4){0.f, 0.f, 0.f, 0.f};
      acc1[i][j] = (f32x4){0.f, 0.f, 0.f, 0.f};
    }

  for (int k0 = 0; k0 < IDIM; k0 += BK) {
    stage_tile(Abase + k0, IDIM, sA, tid);
    stage_tile(B0base + k0, IDIM, sB0, tid);
    stage_tile(B1base + k0, IDIM, sB1, tid);
    __syncthreads();
#pragma unroll
    for (int kk = 0; kk < 2; ++kk) {
      int cbase = kk * 4 + q;
      f16x8 a[4], b0[4], b1[4];
#pragma unroll
      for (int i = 0; i < 4; ++i) a[i] = frag_ld(sA, wr + i * 16 + lr, cbase);
#pragma unroll
      for (int j = 0; j < 4; ++j) {
        b0[j] = frag_ld(sB0, wc + j * 16 + lr, cbase);
        b1[j] = frag_ld(sB1, wc + j * 16 + lr, cbase);
      }
#pragma unroll
      for (int i = 0; i < 4; ++i)
#pragma unroll
        for (int j = 0; j < 4; ++j) {
          acc0[i][j] = __builtin_amdgcn_mfma_f32_16x16x32_f16(a[i], b0[j], acc0[i][j], 0, 0, 0);
          acc1[i][j] = __builtin_amdgcn_mfma_f32_16x16x32_f16(a[i], b1[j], acc1[i][j], 0, 0, 0);
        }
    }
    __syncthreads();
  }

  float scale = ds_p[0] * 256.0f;  // undo the 1/256 on H
#pragma unroll
  for (int i = 0; i < 4; ++i)
#pragma unroll
    for (int j = 0; j < 4; ++j)
#pragma unroll
      for (int r = 0; r < 4; ++r) {
        long m = (long)bm * BM + wr + i * 16 + q * 4 + r;
        long n = (long)bn * 256 + wc + j * 16 + lr;
        Out[m * DDIM + n] = acc0[i][j][r] * scale;
        Out[m * DDIM + n + 128] = acc1[i][j][r] * scale;
      }
}

// ---------------- launch ----------------
// ws layout (bytes):
//   x_f16:   [0,          67108864)
//   gate_f16:[67108864,   157286400)
//   up_f16:  [157286400,  247463936)
//   down_f16:[247463936,  337641472)
//   h_f16:   [337641472,  517996544)
extern "C" void kernel_launch(void* const* d_in, const int* in_sizes, int n_in,
                              void* d_out, int out_size, void* d_ws, size_t ws_size,
                              hipStream_t stream) {
  const float* x  = (const float*)d_in[0];
  const int*   gw = (const int*)d_in[1];
  const float* gs = (const float*)d_in[2];
  const int*   uw = (const int*)d_in[3];
  const float* us = (const float*)d_in[4];
  const int*   dw = (const int*)d_in[5];
  const float* ds = (const float*)d_in[6];
  float* out = (float*)d_out;

  char* ws = (char*)d_ws;
  _Float16* xf  = (_Float16*)(ws);
  _Float16* gwf = (_Float16*)(ws + 67108864L);
  _Float16* uwf = (_Float16*)(ws + 157286400L);
  _Float16* dwf = (_Float16*)(ws + 247463936L);
  _Float16* h   = (_Float16*)(ws + 337641472L);

  cvt_x_kernel<<<2048, 256, 0, stream>>>(x, xf, (MTOK * DDIM) / 4);
  cvt_w_kernel<<<2048, 256, 0, stream>>>(gw, gwf, (IDIM * DDIM) / 4);
  cvt_w_kernel<<<2048, 256, 0, stream>>>(uw, uwf, (IDIM * DDIM) / 4);
  cvt_w_kernel<<<2048, 256, 0, stream>>>(dw, dwf, (DDIM * IDIM) / 4);

  dim3 g1(MTOK / BM, IDIM / BN);  // 64 x 86
  gemm_gateup<<<g1, 256, 0, stream>>>(xf, gwf, uwf, gs, us, h);

  dim3 g2(MTOK / BM, DDIM / 256);  // 64 x 16
  gemm_down<<<g2, 256, 0, stream>>>(h, dwf, ds, out);
}